// Round 1
// baseline (16420.959 us; speedup 1.0000x reference)
//
#include <hip/hip_runtime.h>

typedef unsigned int u32;
typedef unsigned short u16;
typedef short bfrag __attribute__((ext_vector_type(8)));   // 8 x bf16 (4 VGPR)
typedef float f4 __attribute__((ext_vector_type(4)));

#define HID 512
#define SEQT 1024
#define NIN 10
#define NC 9
#define NCL 16          // clusters
#define GW  16          // workgroups per cluster
#define MB  16          // batch rows per cluster
#define KSN 17          // k-steps: 16 x (K=32 over H) + 1 x (x|1|pad)
#define COLS 544        // 512 h + 10 x + 1 one + 21 pad  (bf16)
#define XC0 512
#define ONECOL 522

#define WPACK_U16 (16*4*2*KSN*64*8)
#define WPACK_BYTES (WPACK_U16*2)
#define HEX_U16 (NCL*2*MB*COLS)
#define HEX_BYTES (HEX_U16*2)

__device__ __forceinline__ u16 f2b(float f){
  u32 u = __float_as_uint(f);
  return (u16)((u + 0x7fffu + ((u>>16)&1u)) >> 16);   // RNE
}
__device__ __forceinline__ float b2f(u16 b){ return __uint_as_float(((u32)b)<<16); }
__device__ __forceinline__ float sigm(float x){ return 1.f/(1.f+__expf(-x)); }
__device__ __forceinline__ float tanh_(float x){ float e=__expf(2.f*x); return 1.f - 2.f/(e+1.f); }

// ---------------- pack W_hh/W_ih/bias into MFMA B-fragment order ----------------
// Wpack[g][w][p][ks][lane][e]  (bf16), flat 16B chunks, one thread per chunk.
// B-frag: col c2 = lane&15 (output within 16-wide ntile), k = (lane>>4)*8+e.
// ntile pair p: p==0 -> [i(8), f(8)], p==1 -> [g(8), o(8)] for h-indices jb..jb+7,
// jb = g*32 + w*8.  ks<16: W_hh[R][ks*32+k]; ks==16: k<10 -> W_ih[R][k],
// k==10 -> b_ih[R]+b_hh[R], else 0.
__global__ void pack_kernel(const float* __restrict__ W_ih, const float* __restrict__ W_hh,
                            const float* __restrict__ b_ih, const float* __restrict__ b_hh,
                            u16* __restrict__ Wpack)
{
  int tid = blockIdx.x*256 + threadIdx.x;
  if (tid >= 16*4*2*KSN*64) return;
  int lane = tid & 63;
  int rest = tid >> 6;
  int ks = rest % KSN; rest /= KSN;
  int p = rest & 1; rest >>= 1;
  int w = rest & 3; rest >>= 2;
  int g = rest;                       // 0..15
  int c2 = lane & 15;
  int kb = lane >> 4;
  int j = g*32 + w*8 + (c2 & 7);
  int gate = (p ? 2 : 0) + (c2 >= 8 ? 1 : 0);   // i,f,g,o = 0,1,2,3
  int R = gate*HID + j;

  union { u16 s[8]; bfrag v; } o;
  if (ks < 16) {
    const float* src = W_hh + (size_t)R*HID + ks*32 + kb*8;
    #pragma unroll
    for (int e=0;e<8;e++) o.s[e] = f2b(src[e]);
  } else {
    #pragma unroll
    for (int e=0;e<8;e++) {
      int k = kb*8 + e;
      float v = (k < NIN) ? W_ih[(size_t)R*NIN + k] : (k==NIN ? (b_ih[R]+b_hh[R]) : 0.f);
      o.s[e] = f2b(v);
    }
  }
  *(bfrag*)(Wpack + (size_t)tid*8) = o.v;
}

// ---------------- init exchange buffers + flags ----------------
// h_ex[cluster][buf][row(16)][col(544)] bf16. buf0 = state s_0 = 0, x_0 in cols
// 512..521, 1.0 at col 522, pad 0. buf1: x cols overwritten at t=0; pads init'd.
__global__ void init_kernel(const float* __restrict__ inputs, u16* __restrict__ hex_,
                            u32* __restrict__ flags)
{
  int tid = blockIdx.x*256 + threadIdx.x;
  if (tid < HEX_U16) {
    int col = tid % COLS;
    int rest = tid / COLS;
    int row = rest % MB; rest /= MB;
    int buf = rest & 1;
    int c = rest >> 1;
    u16 v = 0;
    if (col >= XC0) {
      if (col == ONECOL) v = f2b(1.0f);
      else if (col < ONECOL) {     // x value slot
        if (buf == 0) v = f2b(inputs[((size_t)(c*MB+row)*SEQT + 0)*NIN + (col-XC0)]);
      }
    }
    hex_[tid] = v;
  }
  if (tid < NCL*32) flags[tid] = 0;
}

// ---------------- persistent LSTM kernel ----------------
// grid = 256 blocks (1/CU), 256 threads (4 waves). cluster = bid>>4, rank g = bid&15.
// Wave w owns ntiles {2w, 2w+1} = h-indices jb..jb+7, all 4 gates.
__global__ __launch_bounds__(256, 1) void lstm_kernel(
    const float* __restrict__ inputs, const float* __restrict__ lin_W,
    const float* __restrict__ lin_b, const u16* __restrict__ Wpack,
    u16* __restrict__ hex_, u32* __restrict__ flags, float* __restrict__ out)
{
  const int bid = blockIdx.x;
  const int c = bid >> 4;
  const int g = bid & 15;
  const int tid = threadIdx.x;
  const int w = tid >> 6;
  const int lane = tid & 63;
  const int c2 = lane & 15;
  const int kb = lane >> 4;
  const int jb = g*32 + w*8;
  const bool lowhalf = (c2 < 8);

  __shared__ __align__(16) u16 rowbuf[2][COLS];   // row-g h, parity double-buffered

  // persistent B-fragments: 2 ntiles x 17 ksteps x 4 VGPR = 136 VGPR/lane
  bfrag wf0[KSN], wf1[KSN];
  {
    const u16* base = Wpack + ((size_t)(g*4+w)*2)*KSN*64*8;
    #pragma unroll
    for (int ks=0;ks<KSN;ks++) wf0[ks] = *(const bfrag*)(base + ((size_t)(0*KSN+ks)*64 + lane)*8);
    #pragma unroll
    for (int ks=0;ks<KSN;ks++) wf1[ks] = *(const bfrag*)(base + ((size_t)(1*KSN+ks)*64 + lane)*8);
  }
  // logits weights: waves 0..2 take 3 classes each; lane covers k = lane*8..+8
  float lw[3][8]; float lb[3];
  if (w < 3) {
    #pragma unroll
    for (int cc=0;cc<3;cc++){
      int cls = w*3+cc;
      lb[cc] = lin_b[cls];
      #pragma unroll
      for (int e=0;e<8;e++) lw[cc][e] = lin_W[(size_t)cls*HID + lane*8 + e];
    }
  }

  float cst[4] = {0.f,0.f,0.f,0.f};   // c-state: 4 batch rows, h-index jb+(c2&7)

  const size_t exstride = (size_t)MB*COLS;
  u16* ex0 = hex_ + (size_t)(c*2+0)*exstride;
  u16* ex1 = hex_ + (size_t)(c*2+1)*exstride;
  u32* flg = flags + c*32;

  for (int t = 0; t < SEQT; ++t) {
    // ---- wait for generation t (all 16 slices of this cluster)
    if (lane < 16) {
      while (__hip_atomic_load(&flg[lane], __ATOMIC_RELAXED, __HIP_MEMORY_SCOPE_AGENT) < (u32)t) { }
    }
    __builtin_amdgcn_fence(__ATOMIC_ACQUIRE, "agent");

    const u16* cur = (t & 1) ? ex1 : ex0;
    u16*       nxt = (t & 1) ? ex0 : ex1;

    // ---- A-fragments straight from exchange buffer (row = c2, k-chunk = kb)
    bfrag a[KSN];
    #pragma unroll
    for (int ks=0;ks<KSN;ks++)
      a[ks] = *(const bfrag*)(cur + (size_t)c2*COLS + ks*32 + kb*8);

    // prefetch next x (wave0 lanes 0..9); consumed after MFMA
    float xv = 0.f;
    if (w==0 && lane < NIN && t+1 < SEQT)
      xv = inputs[((size_t)bid*SEQT + (t+1))*NIN + lane];

    // wave3 stashes row-g h into LDS for the (off-critical-path) logits
    if (w == 3) {
      #pragma unroll
      for (int ks=0;ks<KSN;ks++)
        if (c2 == g) *(bfrag*)(&rowbuf[t&1][ks*32 + kb*8]) = a[ks];
    }

    // ---- gates = [h | x,1] @ Wpack^T   (f32 accum)
    f4 acc0 = {0.f,0.f,0.f,0.f}, acc1 = {0.f,0.f,0.f,0.f};
    #pragma unroll
    for (int ks=0;ks<KSN;ks++){
      acc0 = __builtin_amdgcn_mfma_f32_16x16x32_bf16(a[ks], wf0[ks], acc0, 0,0,0);
      acc1 = __builtin_amdgcn_mfma_f32_16x16x32_bf16(a[ks], wf1[ks], acc1, 0,0,0);
    }

    // ---- activations. lanes c2<8: acc0=i, acc1=g ; c2>=8: acc0=f, acc1=o.
    u16 hb[4];
    #pragma unroll
    for (int r=0;r<4;r++){
      float a0 = sigm(acc0[r]);
      float a1 = lowhalf ? tanh_(acc1[r]) : sigm(acc1[r]);
      float p0 = __shfl_xor(a0, 8, 64);
      float p1 = __shfl_xor(a1, 8, 64);
      float ii = lowhalf ? a0 : p0;
      float ff = lowhalf ? p0 : a0;
      float gg = lowhalf ? a1 : p1;
      float oo = lowhalf ? p1 : a1;
      float cn = ff*cst[r] + ii*gg;
      cst[r] = cn;
      hb[r] = f2b(oo * tanh_(cn));
    }

    // ---- publish h slice (pair-packed dword stores), rows = kb*4+r, col jb+c2
    #pragma unroll
    for (int r=0;r<4;r++){
      u32 nb = (u32)(u16)__shfl_down((int)hb[r], 1, 64);
      if (lowhalf && !(c2 & 1)) {
        u32 pv = (u32)hb[r] | (nb << 16);
        *(u32*)(nxt + (size_t)(kb*4+r)*COLS + jb + c2) = pv;
      }
    }
    // x_{t+1} for this WG's batch row
    if (w==0 && lane < NIN && t+1 < SEQT)
      nxt[(size_t)g*COLS + XC0 + lane] = f2b(xv);

    __syncthreads();    // S1: all slice/x stores drained, rowbuf ready
    if (tid == 0)
      __hip_atomic_store(&flg[g], (u32)(t+1), __ATOMIC_RELEASE, __HIP_MEMORY_SCOPE_AGENT);

    // ---- logits[t-1] = s_t[row g] . lin_W^T + lin_b   (waves 0..2, from LDS)
    if (w < 3 && t > 0) {
      bfrag hx = *(const bfrag*)(&rowbuf[t&1][lane*8]);
      float hv[8];
      #pragma unroll
      for (int e=0;e<8;e++) hv[e] = b2f((u16)hx[e]);
      #pragma unroll
      for (int cc=0;cc<3;cc++){
        float s = 0.f;
        #pragma unroll
        for (int e=0;e<8;e++) s += hv[e]*lw[cc][e];
        #pragma unroll
        for (int off=1;off<64;off<<=1) s += __shfl_xor(s, off, 64);
        if (lane == 0)
          out[((size_t)bid*SEQT + (t-1))*NC + (w*3+cc)] = s + lb[cc];
      }
    }
  }

  // ---- epilogue: logits[SEQT-1] from s_SEQT (buf parity SEQT&1 == 0)
  if (lane < 16) {
    while (__hip_atomic_load(&flg[lane], __ATOMIC_RELAXED, __HIP_MEMORY_SCOPE_AGENT) < (u32)SEQT) { }
  }
  __builtin_amdgcn_fence(__ATOMIC_ACQUIRE, "agent");
  if (w < 3) {
    const u16* cur = ex0;
    bfrag hx = *(const bfrag*)(cur + (size_t)g*COLS + lane*8);
    float hv[8];
    #pragma unroll
    for (int e=0;e<8;e++) hv[e] = b2f((u16)hx[e]);
    #pragma unroll
    for (int cc=0;cc<3;cc++){
      float s = 0.f;
      #pragma unroll
      for (int e=0;e<8;e++) s += hv[e]*lw[cc][e];
      #pragma unroll
      for (int off=1;off<64;off<<=1) s += __shfl_xor(s, off, 64);
      if (lane == 0)
        out[((size_t)bid*SEQT + (SEQT-1))*NC + (w*3+cc)] = s + lb[cc];
    }
  }
}

extern "C" void kernel_launch(void* const* d_in, const int* in_sizes, int n_in,
                              void* d_out, int out_size, void* d_ws, size_t ws_size,
                              hipStream_t stream)
{
  const float* inputs = (const float*)d_in[0];
  const float* W_ih   = (const float*)d_in[1];
  const float* W_hh   = (const float*)d_in[2];
  const float* b_ih   = (const float*)d_in[3];
  const float* b_hh   = (const float*)d_in[4];
  const float* lin_W  = (const float*)d_in[5];
  const float* lin_b  = (const float*)d_in[6];

  u16* Wpack = (u16*)d_ws;
  u16* hex_  = (u16*)((char*)d_ws + WPACK_BYTES);
  u32* flags = (u32*)((char*)d_ws + WPACK_BYTES + HEX_BYTES);

  pack_kernel<<<(16*4*2*KSN*64 + 255)/256, 256, 0, stream>>>(W_ih, W_hh, b_ih, b_hh, Wpack);
  init_kernel<<<(HEX_U16 + 255)/256, 256, 0, stream>>>(inputs, hex_, flags);
  lstm_kernel<<<256, 256, 0, stream>>>(inputs, lin_W, lin_b, Wpack, hex_, flags, (float*)d_out);
}

// Round 3
// 3480.676 us; speedup vs baseline: 4.7178x; 4.7178x over previous
//
#include <hip/hip_runtime.h>

typedef unsigned int u32;
typedef unsigned long long u64;
typedef unsigned short u16;
typedef short bfrag __attribute__((ext_vector_type(8)));   // 8 x bf16 (4 VGPR)
typedef float f4 __attribute__((ext_vector_type(4)));
typedef u32 u32x4 __attribute__((ext_vector_type(4)));

#define HID 512
#define SEQT 1024
#define NIN 10
#define NC 9
#define NCL 16          // clusters
#define MB  16          // batch rows per cluster
#define KSN 17          // k-steps: 16 x (K=32 over H) + 1 x (x|1|pad)
#define COLS 544        // 512 h + 10 x + 1 one + 21 pad  (bf16)
#define XC0 512
#define ONECOL 522
#define LROW 552        // LDS panel row stride (u16)

#define WPACK_U16 (16*4*2*KSN*64*8)
#define WPACK_BYTES (WPACK_U16*2)
#define HEX_U16 (NCL*2*MB*COLS)
#define HEX_BYTES (HEX_U16*2)
#define FLAGS_U32 (NCL*64)         // 16 flags used per cluster, 256B apart per cluster
#define FLAGS_BYTES (FLAGS_U32*4)

__device__ __forceinline__ u16 f2b(float f){
  u32 u = __float_as_uint(f);
  return (u16)((u + 0x7fffu + ((u>>16)&1u)) >> 16);   // RNE
}
__device__ __forceinline__ float b2f(u16 b){ return __uint_as_float(((u32)b)<<16); }
__device__ __forceinline__ float sigm(float x){ return 1.f/(1.f+__expf(-x)); }
__device__ __forceinline__ float tanh_(float x){ float e=__expf(2.f*x); return 1.f - 2.f/(e+1.f); }

// ---- system-scope (IC-coherent, L1+L2 bypass) ops. Explicit vmcnt inside asm:
// the compiler does NOT track inline-asm memory ops (round-2 lesson).
__device__ __forceinline__ u32 ldflag(u64 base, u32 off){
  u32 r;
  asm volatile("global_load_dword %0, %1, %2 sc0 sc1\n\ts_waitcnt vmcnt(0)"
               : "=&v"(r) : "v"(off), "s"(base) : "memory");
  return r;
}
__device__ __forceinline__ void st32_sys(u64 base, u32 off, u32 v){
  asm volatile("global_store_dword %0, %1, %2 sc0 sc1"
               :: "v"(off), "v"(v), "s"(base) : "memory");
}
__device__ __forceinline__ void st16_sys(u64 base, u32 off, u16 v){
  asm volatile("global_store_short %0, %1, %2 sc0 sc1"
               :: "v"(off), "v"((u32)v), "s"(base) : "memory");
}
__device__ __forceinline__ void drain_vm(){
  asm volatile("s_waitcnt vmcnt(0)" ::: "memory");
}
__device__ __forceinline__ void spin_flags(u64 flgb, u32 foff, u32 tgt){
  int guard = 0;
  for(;;){
    u32 v = ldflag(flgb, foff);
    if (__all((int)(v >= tgt))) break;
    if (++guard > 50000) break;           // fail loudly, never hang
  }
}

// ---------------- pack W_hh/W_ih/bias into MFMA B-fragment order ----------------
__global__ void pack_kernel(const float* __restrict__ W_ih, const float* __restrict__ W_hh,
                            const float* __restrict__ b_ih, const float* __restrict__ b_hh,
                            u16* __restrict__ Wpack)
{
  int tid = blockIdx.x*256 + threadIdx.x;
  if (tid >= 16*4*2*KSN*64) return;
  int lane = tid & 63;
  int rest = tid >> 6;
  int ks = rest % KSN; rest /= KSN;
  int p = rest & 1; rest >>= 1;
  int w = rest & 3; rest >>= 2;
  int g = rest;                       // 0..15
  int c2 = lane & 15;
  int kb = lane >> 4;
  int j = g*32 + w*8 + (c2 & 7);
  int gate = (p ? 2 : 0) + (c2 >= 8 ? 1 : 0);   // i,f,g,o = 0,1,2,3
  int R = gate*HID + j;

  union { u16 s[8]; bfrag v; } o;
  if (ks < 16) {
    const float* src = W_hh + (size_t)R*HID + ks*32 + kb*8;
    #pragma unroll
    for (int e=0;e<8;e++) o.s[e] = f2b(src[e]);
  } else {
    #pragma unroll
    for (int e=0;e<8;e++) {
      int k = kb*8 + e;
      float v = (k < NIN) ? W_ih[(size_t)R*NIN + k] : (k==NIN ? (b_ih[R]+b_hh[R]) : 0.f);
      o.s[e] = f2b(v);
    }
  }
  *(bfrag*)(Wpack + (size_t)tid*8) = o.v;
}

// ---------------- init exchange buffers + flags ----------------
__global__ void init_kernel(const float* __restrict__ inputs, u16* __restrict__ hex_,
                            u32* __restrict__ flags)
{
  int tid = blockIdx.x*256 + threadIdx.x;
  if (tid < HEX_U16) {
    int col = tid % COLS;
    int rest = tid / COLS;
    int row = rest % MB; rest /= MB;
    int buf = rest & 1;
    int c = rest >> 1;
    u16 v = 0;
    if (col >= XC0) {
      if (col == ONECOL) v = f2b(1.0f);
      else if (col < ONECOL) {
        if (buf == 0) v = f2b(inputs[((size_t)(c*MB+row)*SEQT + 0)*NIN + (col-XC0)]);
      }
    }
    hex_[tid] = v;
  }
  if (tid < FLAGS_U32) flags[tid] = 0;
}

// ---------------- persistent LSTM kernel ----------------
// grid = 256 blocks (1/CU), 256 threads (4 waves). cluster = bid>>4, rank g = bid&15.
// All inter-block traffic via sc0 sc1 (Infinity-Cache coherent) — no fences.
__global__ __launch_bounds__(256, 1) void lstm_kernel(
    const float* __restrict__ inputs, const float* __restrict__ lin_W,
    const float* __restrict__ lin_b, const u16* __restrict__ Wpack,
    u16* __restrict__ hex_, u32* __restrict__ flags, float* __restrict__ out)
{
  const int bid = blockIdx.x;
  const int cl = bid >> 4;
  const int g = bid & 15;
  const int tid = threadIdx.x;
  const int w = tid >> 6;
  const int lane = tid & 63;
  const int c2 = lane & 15;
  const int kb = lane >> 4;
  const int jb = g*32 + w*8;
  const bool lowhalf = (c2 < 8);
  const int vb = cl*MB + g;              // batch row / output row

  __shared__ __align__(16) u16 panel[MB*LROW];

  // persistent B-fragments: 2 ntiles x 17 ksteps = 136 VGPR/lane
  bfrag wf0[KSN], wf1[KSN];
  {
    const u16* base = Wpack + ((size_t)(g*4+w)*2)*KSN*64*8;
    #pragma unroll
    for (int ks=0;ks<KSN;ks++) wf0[ks] = *(const bfrag*)(base + ((size_t)ks*64 + lane)*8);
    #pragma unroll
    for (int ks=0;ks<KSN;ks++) wf1[ks] = *(const bfrag*)(base + ((size_t)(KSN+ks)*64 + lane)*8);
  }
  float lw[3][8]; float lb[3];
  if (w < 3) {
    #pragma unroll
    for (int cc=0;cc<3;cc++){
      int cls = w*3+cc;
      lb[cc] = lin_b[cls];
      #pragma unroll
      for (int e=0;e<8;e++) lw[cc][e] = lin_W[(size_t)cls*HID + lane*8 + e];
    }
  }

  float cst[4] = {0.f,0.f,0.f,0.f};

  const u64 ex0 = (u64)(hex_ + (size_t)(cl*2+0)*MB*COLS);
  const u64 ex1 = (u64)(hex_ + (size_t)(cl*2+1)*MB*COLS);
  const u64 flgb = (u64)(flags + (size_t)cl*64);
  const u32 foff = (u32)(c2*4);

  // precompute stage chunk offsets (parity-independent)
  u32 goff[4], loff[4], goff4, loff4;
  #pragma unroll
  for (int i=0;i<4;i++){
    u32 chunk = (u32)tid + (u32)i*256u;
    u32 row = chunk / 68u, rem = chunk - row*68u;
    goff[i] = row*1088u + rem*16u;
    loff[i] = row*(LROW*2u) + rem*16u;
  }
  {
    u32 chunk = 1024u + (u32)lane;
    u32 row = chunk / 68u, rem = chunk - row*68u;
    goff4 = row*1088u + rem*16u;
    loff4 = row*(LROW*2u) + rem*16u;
  }

  for (int t = 0; t < SEQT; ++t) {
    const u64 cur = (t & 1) ? ex1 : ex0;
    const u64 nxt = (t & 1) ? ex0 : ex1;

    // ---- all waves spin until every slice of generation t is published
    spin_flags(flgb, foff, (u32)t);

    // ---- stage cur panel (16 rows x 1088B) into LDS, IC-coherent loads
    {
      u32x4 r0,r1,r2,r3;
      if (w == 3) {
        u32x4 r4;
        asm volatile(
          "global_load_dwordx4 %0, %5, %10 sc0 sc1\n\t"
          "global_load_dwordx4 %1, %6, %10 sc0 sc1\n\t"
          "global_load_dwordx4 %2, %7, %10 sc0 sc1\n\t"
          "global_load_dwordx4 %3, %8, %10 sc0 sc1\n\t"
          "global_load_dwordx4 %4, %9, %10 sc0 sc1\n\t"
          "s_waitcnt vmcnt(0)"
          : "=&v"(r0), "=&v"(r1), "=&v"(r2), "=&v"(r3), "=&v"(r4)
          : "v"(goff[0]), "v"(goff[1]), "v"(goff[2]), "v"(goff[3]), "v"(goff4), "s"(cur)
          : "memory");
        *(u32x4*)((char*)panel + loff[0]) = r0;
        *(u32x4*)((char*)panel + loff[1]) = r1;
        *(u32x4*)((char*)panel + loff[2]) = r2;
        *(u32x4*)((char*)panel + loff[3]) = r3;
        *(u32x4*)((char*)panel + loff4)   = r4;
      } else {
        asm volatile(
          "global_load_dwordx4 %0, %4, %8 sc0 sc1\n\t"
          "global_load_dwordx4 %1, %5, %8 sc0 sc1\n\t"
          "global_load_dwordx4 %2, %6, %8 sc0 sc1\n\t"
          "global_load_dwordx4 %3, %7, %8 sc0 sc1\n\t"
          "s_waitcnt vmcnt(0)"
          : "=&v"(r0), "=&v"(r1), "=&v"(r2), "=&v"(r3)
          : "v"(goff[0]), "v"(goff[1]), "v"(goff[2]), "v"(goff[3]), "s"(cur)
          : "memory");
        *(u32x4*)((char*)panel + loff[0]) = r0;
        *(u32x4*)((char*)panel + loff[1]) = r1;
        *(u32x4*)((char*)panel + loff[2]) = r2;
        *(u32x4*)((char*)panel + loff[3]) = r3;
      }
    }
    __syncthreads();                     // S1: panel ready

    // prefetch next x (wave0 lanes 0..9), normal cached load
    float xv = 0.f;
    if (w==0 && lane < NIN && t+1 < SEQT)
      xv = inputs[((size_t)vb*SEQT + (t+1))*NIN + lane];

    // grab row-g h into regs now; heavy logit math runs after the flag release
    bfrag hx;
    if (w < 3) hx = *(const bfrag*)&panel[g*LROW + lane*8];

    // ---- gates = [h | x,1] @ Wpack^T   (f32 accum), A-frags from LDS
    f4 acc0 = {0.f,0.f,0.f,0.f}, acc1 = {0.f,0.f,0.f,0.f};
    #pragma unroll
    for (int ks=0;ks<KSN;ks++){
      bfrag av = *(const bfrag*)&panel[c2*LROW + ks*32 + kb*8];
      acc0 = __builtin_amdgcn_mfma_f32_16x16x32_bf16(av, wf0[ks], acc0, 0,0,0);
      acc1 = __builtin_amdgcn_mfma_f32_16x16x32_bf16(av, wf1[ks], acc1, 0,0,0);
    }

    // ---- activations. lanes c2<8: acc0=i, acc1=g ; c2>=8: acc0=f, acc1=o.
    u16 hb[4];
    #pragma unroll
    for (int r=0;r<4;r++){
      float a0 = sigm(acc0[r]);
      float a1 = lowhalf ? tanh_(acc1[r]) : sigm(acc1[r]);
      float p0 = __shfl_xor(a0, 8, 64);
      float p1 = __shfl_xor(a1, 8, 64);
      float ii = lowhalf ? a0 : p0;
      float ff = lowhalf ? p0 : a0;
      float gg = lowhalf ? a1 : p1;
      float oo = lowhalf ? p1 : a1;
      float cn = ff*cst[r] + ii*gg;
      cst[r] = cn;
      hb[r] = f2b(oo * tanh_(cn));
    }

    // ---- publish h slice (pair-packed dword stores, IC-coherent)
    #pragma unroll
    for (int r=0;r<4;r++){
      u32 nb = (u32)(u16)__shfl_down((int)hb[r], 1, 64);
      if (lowhalf && !(c2 & 1)) {
        u32 pv = (u32)hb[r] | (nb << 16);
        st32_sys(nxt, (u32)(((kb*4+r)*COLS + jb + c2)*2), pv);
      }
    }
    if (w==0 && lane < NIN && t+1 < SEQT)
      st16_sys(nxt, (u32)((g*COLS + XC0 + lane)*2), f2b(xv));

    drain_vm();                          // explicit: asm stores are untracked
    __syncthreads();                     // S2: every wave drained its stores
    if (tid == 0)
      st32_sys(flgb, (u32)(g*4), (u32)(t+1));

    // ---- logits[t-1] from hx (registers only -> no race with next staging)
    if (w < 3 && t > 0) {
      float hv[8];
      #pragma unroll
      for (int e=0;e<8;e++) hv[e] = b2f((u16)hx[e]);
      #pragma unroll
      for (int cc=0;cc<3;cc++){
        float s = 0.f;
        #pragma unroll
        for (int e=0;e<8;e++) s += hv[e]*lw[cc][e];
        #pragma unroll
        for (int off=1;off<64;off<<=1) s += __shfl_xor(s, off, 64);
        if (lane == 0)
          out[((size_t)vb*SEQT + (t-1))*NC + (w*3+cc)] = s + lb[cc];
      }
    }
  }

  // ---- epilogue: logits[SEQT-1] from h_SEQT (in ex0; SEQT even)
  spin_flags(flgb, foff, (u32)SEQT);
  if (w < 3) {
    u32x4 rr;
    asm volatile("global_load_dwordx4 %0, %1, %2 sc0 sc1\n\ts_waitcnt vmcnt(0)"
                 : "=&v"(rr) : "v"((u32)((g*COLS + lane*8)*2)), "s"(ex0) : "memory");
    float hv[8];
    #pragma unroll
    for (int e=0;e<4;e++){
      hv[2*e]   = b2f((u16)(rr[e] & 0xffffu));
      hv[2*e+1] = b2f((u16)(rr[e] >> 16));
    }
    #pragma unroll
    for (int cc=0;cc<3;cc++){
      float s = 0.f;
      #pragma unroll
      for (int e=0;e<8;e++) s += hv[e]*lw[cc][e];
      #pragma unroll
      for (int off=1;off<64;off<<=1) s += __shfl_xor(s, off, 64);
      if (lane == 0)
        out[((size_t)vb*SEQT + (SEQT-1))*NC + (w*3+cc)] = s + lb[cc];
    }
  }
}

extern "C" void kernel_launch(void* const* d_in, const int* in_sizes, int n_in,
                              void* d_out, int out_size, void* d_ws, size_t ws_size,
                              hipStream_t stream)
{
  const float* inputs = (const float*)d_in[0];
  const float* W_ih   = (const float*)d_in[1];
  const float* W_hh   = (const float*)d_in[2];
  const float* b_ih   = (const float*)d_in[3];
  const float* b_hh   = (const float*)d_in[4];
  const float* lin_W  = (const float*)d_in[5];
  const float* lin_b  = (const float*)d_in[6];

  u16* Wpack = (u16*)d_ws;
  u16* hex_  = (u16*)((char*)d_ws + WPACK_BYTES);
  u32* flags = (u32*)((char*)d_ws + WPACK_BYTES + HEX_BYTES);

  pack_kernel<<<(16*4*2*KSN*64 + 255)/256, 256, 0, stream>>>(W_ih, W_hh, b_ih, b_hh, Wpack);
  init_kernel<<<(HEX_U16 + 255)/256, 256, 0, stream>>>(inputs, hex_, flags);
  lstm_kernel<<<256, 256, 0, stream>>>(inputs, lin_W, lin_b, Wpack, hex_, flags, (float*)d_out);
}